// Round 5
// baseline (212.780 us; speedup 1.0000x reference)
//
#include <hip/hip_runtime.h>
#include <math.h>

#define B_ 4
#define L_ 4096
#define D_ 256
#define A_ 64
#define M_ (B_*L_)   // 16384 flat rows

typedef _Float16 half4 __attribute__((ext_vector_type(4)));
typedef _Float16 half8 __attribute__((ext_vector_type(8)));
typedef __attribute__((ext_vector_type(4))) float floatx4;

__device__ __forceinline__ unsigned short f2h_(float f) {
    _Float16 h = (_Float16)f;
    return __builtin_bit_cast(unsigned short, h);
}

// ---------------------------------------------------------------------------
// wconv: W f32 [256][64] -> W^T fp16 [64][256]. Wq scaled by 1/ln2 (exp2
// softmax domain). grid (3), block 256.
// ---------------------------------------------------------------------------
__global__ __launch_bounds__(256) void wconv_kernel(
    const float* __restrict__ Wq, const float* __restrict__ Wk,
    const float* __restrict__ Wv, unsigned short* __restrict__ wt)
{
    const int w = blockIdx.x, t = threadIdx.x;
    const float* W = (w == 0) ? Wq : (w == 1) ? Wk : Wv;
    unsigned short* o = wt + w * A_ * D_;
    const float scale = (w == 0) ? 1.44269504f : 1.0f;
    __shared__ float T[A_ * 260];
    #pragma unroll
    for (int p = 0; p < 16; ++p) {
        int idx = p * 256 + t;
        int d = idx >> 4, a4 = (idx & 15) * 4;
        float4 v = *(const float4*)(W + d * A_ + a4);
        T[(a4 + 0) * 260 + d] = v.x * scale;
        T[(a4 + 1) * 260 + d] = v.y * scale;
        T[(a4 + 2) * 260 + d] = v.z * scale;
        T[(a4 + 3) * 260 + d] = v.w * scale;
    }
    __syncthreads();
    const int a = t >> 2, d0 = (t & 3) * 64;
    #pragma unroll
    for (int i = 0; i < 16; ++i) {
        float4 v = *(const float4*)(&T[a * 260 + d0 + 4 * i]);
        ushort4 s;
        s.x = f2h_(v.x); s.y = f2h_(v.y); s.z = f2h_(v.z); s.w = f2h_(v.w);
        *(ushort4*)(o + a * D_ + d0 + 4 * i) = s;
    }
}

// ---------------------------------------------------------------------------
// proj (MFMA): q/k fp16 [M][64]; v fp16 TRANSPOSED [B][64][L].
// grid (M/64, 3), block 256 = 4 waves (16 rows each).
// W^T fragments read directly from global (32 KB, L2-resident).
// C routed through LDS (transposed for v) -> coalesced uint4 global stores.
// ---------------------------------------------------------------------------
__global__ __launch_bounds__(256) void proj_kernel(
    const float* __restrict__ x,           // [M][256] f32
    const unsigned short* __restrict__ wt, // [3][64][256] fp16 (W^T)
    unsigned short* __restrict__ qo,
    unsigned short* __restrict__ ko,
    unsigned short* __restrict__ vto)
{
    __shared__ __align__(16) unsigned short Xh[64 * 264];
    __shared__ __align__(16) unsigned short Cst[64 * 72];
    const int t = threadIdx.x, m0 = blockIdx.x * 64, w = blockIdx.y;

    #pragma unroll
    for (int p = 0; p < 16; ++p) {
        int idx = p * 1024 + t * 4;
        int row = idx >> 8, col = idx & 255;
        float4 v = *(const float4*)(x + (size_t)(m0 + row) * D_ + col);
        ushort4 s;
        s.x = f2h_(v.x); s.y = f2h_(v.y); s.z = f2h_(v.z); s.w = f2h_(v.w);
        *(ushort4*)(Xh + row * 264 + col) = s;
    }
    __syncthreads();

    const int lane = t & 63, wid = t >> 6, c = lane & 15, g = lane >> 4;
    half8 xa[8];
    #pragma unroll
    for (int s = 0; s < 8; ++s)
        xa[s] = *(const half8*)(Xh + (16 * wid + c) * 264 + 32 * s + 8 * g);

    const unsigned short* wsrc = wt + w * A_ * D_;
    #pragma unroll
    for (int nt = 0; nt < 4; ++nt) {
        floatx4 acc = {0.f, 0.f, 0.f, 0.f};
        #pragma unroll
        for (int s = 0; s < 8; ++s) {
            half8 wb = *(const half8*)(wsrc + (16 * nt + c) * D_ + 32 * s + 8 * g);
            acc = __builtin_amdgcn_mfma_f32_16x16x32_f16(xa[s], wb, acc, 0, 0, 0);
        }
        // C[row=4g+r][col=c]: x-row = m0+16wid+4g+r, a = 16nt+c
        if (w < 2) {
            #pragma unroll
            for (int r = 0; r < 4; ++r)
                Cst[(16 * wid + 4 * g + r) * 72 + 16 * nt + c] = f2h_(acc[r]);
        } else {
            #pragma unroll
            for (int r = 0; r < 4; ++r)
                Cst[(16 * nt + c) * 72 + 16 * wid + 4 * g + r] = f2h_(acc[r]);
        }
    }
    __syncthreads();

    const int row = t >> 2, seg = t & 3;   // 64 rows x 4 segments of 16 shorts
    uint4 d0 = *(const uint4*)(Cst + row * 72 + seg * 16);
    uint4 d1 = *(const uint4*)(Cst + row * 72 + seg * 16 + 8);
    if (w < 2) {
        unsigned short* o = (w == 0) ? qo : ko;
        unsigned short* p = o + (size_t)(m0 + row) * A_ + seg * 16;
        *(uint4*)(p) = d0;
        *(uint4*)(p + 8) = d1;
    } else {
        const int bb = m0 >> 12, l0 = m0 & (L_ - 1);
        unsigned short* p = vto + ((size_t)(bb * A_ + row)) * L_ + l0 + seg * 16;
        *(uint4*)(p) = d0;
        *(uint4*)(p + 8) = d1;
    }
}

// ---------------------------------------------------------------------------
// MFMA flash attention, S^T form, barrier-free main loop, direct-global K/V.
// grid (L/16, B), block 256 = 4 waves = 4 key phases (kt = wid mod 4), all
// waves share the same 16 queries. Phases merged once in the epilogue.
// QK^T: A=K (b128 direct from kb), B=Q -> S^T[key=16nt+4g+r][q=c].
// PV:   A=V^T (b64 direct from vt), B=P^T (= S^T C-layout), K=16 MFMA.
// Softmax: per-lane q row, exp2 domain, shfl_xor 16/32 only.
// ---------------------------------------------------------------------------
__global__ __launch_bounds__(256) void attn_kernel(
    const unsigned short* __restrict__ qb,  // [B][L][64] fp16 (x 1/ln2)
    const unsigned short* __restrict__ kb,  // [B][L][64] fp16
    const unsigned short* __restrict__ vt,  // [B][64][L] fp16
    float* __restrict__ out)                // [B][L][64] f32
{
    __shared__ __align__(16) float4 Obuf[4][4][64];  // [ph][at][lane] 16 KB
    __shared__ float2 mlb[4][64];                    // [ph][lane] 2 KB
    __shared__ float  Ot[16 * 68];                   // un-transpose buf 4.25 KB

    const int t    = threadIdx.x;
    const int lane = t & 63;
    const int wid  = t >> 6;          // key phase
    const int c    = lane & 15;       // q within tile / m-index
    const int g    = lane >> 4;
    const int b    = blockIdx.y;
    const int qt   = (gridDim.x - 1) - blockIdx.x;   // heavy q-tiles first
    const int q0   = qt * 16;
    const int qme  = q0 + c;

    const size_t base  = (size_t)b * L_ * A_;
    const size_t vbase = (size_t)b * A_ * L_;

    // Q fragments (B-operand): d = 32s + 8g + j
    half8 qf[2];
    {
        const unsigned short* qp = qb + base + (size_t)(q0 + c) * A_ + g * 8;
        qf[0] = *(const half8*)(qp);
        qf[1] = *(const half8*)(qp + 32);
    }

    floatx4 O4[4];          // O^T[a=16at+4g+r][q=c], unnormalized
    #pragma unroll
    for (int at = 0; at < 4; ++at) O4[at] = (floatx4){0.f, 0.f, 0.f, 0.f};
    float m_ = -INFINITY, l_ = 0.f;

    const int T = (q0 >> 6) + 1;      // k-tiles needed by this q-block

    for (int kt = wid; kt < T; kt += 4) {
        const int k0 = kt << 6;
        const unsigned short* kp = kb + base + (size_t)k0 * A_;
        const unsigned short* vp = vt + vbase + k0;

        // ---- K fragments (direct global, 16B each) ----
        half8 kf[2][4];
        #pragma unroll
        for (int s = 0; s < 2; ++s)
            #pragma unroll
            for (int nt = 0; nt < 4; ++nt)
                kf[s][nt] = *(const half8*)(kp + (16 * nt + c) * A_ + 32 * s + 8 * g);

        // ---- S^T = K . Q^T ----
        floatx4 S4[4];
        #pragma unroll
        for (int nt = 0; nt < 4; ++nt) S4[nt] = (floatx4){0.f, 0.f, 0.f, 0.f};
        #pragma unroll
        for (int s = 0; s < 2; ++s)
            #pragma unroll
            for (int nt = 0; nt < 4; ++nt)
                S4[nt] = __builtin_amdgcn_mfma_f32_16x16x32_f16(kf[s][nt], qf[s], S4[nt], 0, 0, 0);

        // ---- V fragments (direct global, 8B each) — issue before softmax ----
        half4 vf[4][4];
        #pragma unroll
        for (int at = 0; at < 4; ++at)
            #pragma unroll
            for (int nt = 0; nt < 4; ++nt)
                vf[at][nt] = *(const half4*)(vp + (size_t)(16 * at + c) * L_ + 16 * nt + 4 * g);

        // ---- causal mask (only the last tile straddles the diagonal) ----
        if (kt == T - 1) {
            #pragma unroll
            for (int nt = 0; nt < 4; ++nt)
                #pragma unroll
                for (int r = 0; r < 4; ++r)
                    if (k0 + 16 * nt + 4 * g + r > qme) S4[nt][r] = -INFINITY;
        }

        // ---- online softmax (exp2 domain; per-lane q row) ----
        float tm = fmaxf(fmaxf(fmaxf(S4[0][0], S4[0][1]), fmaxf(S4[0][2], S4[0][3])),
                         fmaxf(fmaxf(S4[1][0], S4[1][1]), fmaxf(S4[1][2], S4[1][3])));
        tm = fmaxf(tm, fmaxf(fmaxf(fmaxf(S4[2][0], S4[2][1]), fmaxf(S4[2][2], S4[2][3])),
                             fmaxf(fmaxf(S4[3][0], S4[3][1]), fmaxf(S4[3][2], S4[3][3]))));
        tm = fmaxf(tm, __shfl_xor(tm, 16));
        tm = fmaxf(tm, __shfl_xor(tm, 32));
        const float mn  = fmaxf(m_, tm);
        const float mnc = fmaxf(mn, -3.0e38f);         // guard -inf - -inf
        const float al  = exp2f(fminf(m_ - mnc, 0.f)); // m_=-inf -> 0
        float rs = 0.f;
        half4 pf[4];
        #pragma unroll
        for (int nt = 0; nt < 4; ++nt) {
            #pragma unroll
            for (int r = 0; r < 4; ++r) {
                float p = exp2f(S4[nt][r] - mnc);      // masked: exp2(-inf)=0
                S4[nt][r] = p;
                rs += p;
            }
            pf[nt][0] = (_Float16)S4[nt][0];
            pf[nt][1] = (_Float16)S4[nt][1];
            pf[nt][2] = (_Float16)S4[nt][2];
            pf[nt][3] = (_Float16)S4[nt][3];
        }
        rs += __shfl_xor(rs, 16);
        rs += __shfl_xor(rs, 32);
        l_ = l_ * al + rs;
        m_ = mn;

        // ---- O^T = O^T*al + V^T . P^T ----
        #pragma unroll
        for (int at = 0; at < 4; ++at) {
            O4[at] *= al;
            O4[at] = __builtin_amdgcn_mfma_f32_16x16x16f16(vf[at][0], pf[0], O4[at], 0, 0, 0);
            O4[at] = __builtin_amdgcn_mfma_f32_16x16x16f16(vf[at][1], pf[1], O4[at], 0, 0, 0);
            O4[at] = __builtin_amdgcn_mfma_f32_16x16x16f16(vf[at][2], pf[2], O4[at], 0, 0, 0);
            O4[at] = __builtin_amdgcn_mfma_f32_16x16x16f16(vf[at][3], pf[3], O4[at], 0, 0, 0);
        }
    }

    // ---- merge 4 key phases, un-transpose, coalesced store ----
    #pragma unroll
    for (int at = 0; at < 4; ++at) {
        float4 v; v.x = O4[at][0]; v.y = O4[at][1]; v.z = O4[at][2]; v.w = O4[at][3];
        Obuf[wid][at][lane] = v;
    }
    float2 ml; ml.x = m_; ml.y = l_;
    mlb[wid][lane] = ml;
    __syncthreads();

    {
        const int at = t >> 6, ls = t & 63;
        const int lc = ls & 15, lg = ls >> 4;
        float mf = fmaxf(fmaxf(mlb[0][ls].x, mlb[1][ls].x),
                         fmaxf(mlb[2][ls].x, mlb[3][ls].x));
        float lf = 0.f;
        float acc[4] = {0.f, 0.f, 0.f, 0.f};
        #pragma unroll
        for (int ph = 0; ph < 4; ++ph) {
            const float wgt = exp2f(mlb[ph][ls].x - mf);   // -inf phase -> 0
            lf += wgt * mlb[ph][ls].y;
            const float4 o = Obuf[ph][at][ls];
            acc[0] += wgt * o.x; acc[1] += wgt * o.y;
            acc[2] += wgt * o.z; acc[3] += wgt * o.w;
        }
        const float inv = 1.f / lf;
        #pragma unroll
        for (int r = 0; r < 4; ++r)
            Ot[lc * 68 + 16 * at + 4 * lg + r] = acc[r] * inv;
    }
    __syncthreads();
    {
        const int q = t >> 4, col = (t & 15) * 4;
        float4 u = *(const float4*)(Ot + q * 68 + col);
        *(float4*)(out + base + (size_t)(q0 + q) * A_ + col) = u;
    }
}

// ---------------------------------------------------------------------------
extern "C" void kernel_launch(void* const* d_in, const int* in_sizes, int n_in,
                              void* d_out, int out_size, void* d_ws, size_t ws_size,
                              hipStream_t stream) {
    const float* x  = (const float*)d_in[0];
    const float* Wq = (const float*)d_in[1];
    const float* Wk = (const float*)d_in[2];
    const float* Wv = (const float*)d_in[3];

    unsigned short* qb = (unsigned short*)d_ws;            // 2 MB each
    unsigned short* kb = qb + (size_t)M_ * A_;
    unsigned short* vt = kb + (size_t)M_ * A_;
    unsigned short* wt = vt + (size_t)M_ * A_;             // 3x32 KB W^T fp16
    float* out = (float*)d_out;

    hipLaunchKernelGGL(wconv_kernel, dim3(3), dim3(256), 0, stream, Wq, Wk, Wv, wt);

    dim3 gp(M_ / 64, 3), bp(256);
    hipLaunchKernelGGL(proj_kernel, gp, bp, 0, stream, x, wt, qb, kb, vt);

    dim3 ga(L_ / 16, B_), ba(256);
    hipLaunchKernelGGL(attn_kernel, ga, ba, 0, stream, qb, kb, vt, out);
}

// Round 6
// 138.062 us; speedup vs baseline: 1.5412x; 1.5412x over previous
//
#include <hip/hip_runtime.h>
#include <math.h>

#define B_ 4
#define L_ 4096
#define D_ 256
#define A_ 64
#define M_ (B_*L_)   // 16384 flat rows

typedef _Float16 half4 __attribute__((ext_vector_type(4)));
typedef _Float16 half8 __attribute__((ext_vector_type(8)));
typedef __attribute__((ext_vector_type(4))) float floatx4;

__device__ __forceinline__ unsigned short f2h_(float f) {
    _Float16 h = (_Float16)f;
    return __builtin_bit_cast(unsigned short, h);
}

// ---------------------------------------------------------------------------
// wconv: W f32 [256][64] -> W^T fp16 [64][256]. Wq scaled by 1/ln2 (exp2
// softmax domain). grid (3), block 256.
// ---------------------------------------------------------------------------
__global__ __launch_bounds__(256) void wconv_kernel(
    const float* __restrict__ Wq, const float* __restrict__ Wk,
    const float* __restrict__ Wv, unsigned short* __restrict__ wt)
{
    const int w = blockIdx.x, t = threadIdx.x;
    const float* W = (w == 0) ? Wq : (w == 1) ? Wk : Wv;
    unsigned short* o = wt + w * A_ * D_;
    const float scale = (w == 0) ? 1.44269504f : 1.0f;
    __shared__ float T[A_ * 260];
    #pragma unroll
    for (int p = 0; p < 16; ++p) {
        int idx = p * 256 + t;
        int d = idx >> 4, a4 = (idx & 15) * 4;
        float4 v = *(const float4*)(W + d * A_ + a4);
        T[(a4 + 0) * 260 + d] = v.x * scale;
        T[(a4 + 1) * 260 + d] = v.y * scale;
        T[(a4 + 2) * 260 + d] = v.z * scale;
        T[(a4 + 3) * 260 + d] = v.w * scale;
    }
    __syncthreads();
    const int a = t >> 2, d0 = (t & 3) * 64;
    #pragma unroll
    for (int i = 0; i < 16; ++i) {
        float4 v = *(const float4*)(&T[a * 260 + d0 + 4 * i]);
        ushort4 s;
        s.x = f2h_(v.x); s.y = f2h_(v.y); s.z = f2h_(v.z); s.w = f2h_(v.w);
        *(ushort4*)(o + a * D_ + d0 + 4 * i) = s;
    }
}

// ---------------------------------------------------------------------------
// proj: one block per 32 x-rows computes ALL 3 projections (x staged once).
// grid (M/32), block 384 = 6 waves: wave = (w = wid>>1, mt = wid&1).
// Each wave: 16 rows x 64 cols, 32 MFMA. Wave-local epilogue via LDS.
// q/k fp16 [M][64]; v fp16 TRANSPOSED [B][64][L].
// ---------------------------------------------------------------------------
__global__ __launch_bounds__(384) void proj_kernel(
    const float* __restrict__ x,           // [M][256] f32
    const unsigned short* __restrict__ wt, // [3][64][256] fp16 (W^T)
    unsigned short* __restrict__ qo,
    unsigned short* __restrict__ ko,
    unsigned short* __restrict__ vto)
{
    __shared__ __align__(16) unsigned short Xh[32 * 264];   // 16.5 KB
    __shared__ __align__(16) unsigned short Cst[6 * 1536];  // 18 KB
    const int t = threadIdx.x, m0 = blockIdx.x * 32;

    // stage x tile 32x256 -> fp16 (2048 float4 over 384 threads)
    #pragma unroll
    for (int p = 0; p < 6; ++p) {
        int idx = p * 384 + t;
        if (idx < 2048) {
            int row = idx >> 6, col = (idx & 63) * 4;
            float4 v = *(const float4*)(x + (size_t)(m0 + row) * D_ + col);
            ushort4 s;
            s.x = f2h_(v.x); s.y = f2h_(v.y); s.z = f2h_(v.z); s.w = f2h_(v.w);
            *(ushort4*)(Xh + row * 264 + col) = s;
        }
    }
    __syncthreads();

    const int wid = t >> 6, lane = t & 63, c = lane & 15, g = lane >> 4;
    const int w = wid >> 1, mt = wid & 1;

    half8 xa[8];
    #pragma unroll
    for (int s = 0; s < 8; ++s)
        xa[s] = *(const half8*)(Xh + (16 * mt + c) * 264 + 32 * s + 8 * g);

    const unsigned short* wsrc = wt + w * A_ * D_;
    unsigned short* Cw = Cst + wid * 1536;
    #pragma unroll
    for (int nt = 0; nt < 4; ++nt) {
        floatx4 acc = {0.f, 0.f, 0.f, 0.f};
        #pragma unroll
        for (int s = 0; s < 8; ++s) {
            half8 wb = *(const half8*)(wsrc + (16 * nt + c) * D_ + 32 * s + 8 * g);
            acc = __builtin_amdgcn_mfma_f32_16x16x32_f16(xa[s], wb, acc, 0, 0, 0);
        }
        // C[m=4g+r][a=16nt+c]
        if (w < 2) {
            #pragma unroll
            for (int r = 0; r < 4; ++r)
                Cw[(4 * g + r) * 72 + 16 * nt + c] = f2h_(acc[r]);      // [m16][72]
        } else {
            #pragma unroll
            for (int r = 0; r < 4; ++r)
                Cw[(16 * nt + c) * 24 + 4 * g + r] = f2h_(acc[r]);      // [a64][24]
        }
    }

    // q/k: wave-local store (wave reads only its own Cst region)
    if (w < 2) {
        unsigned short* o = (w == 0) ? qo : ko;
        const int row16 = lane >> 2, seg = lane & 3;
        uint4 d0 = *(const uint4*)(Cw + row16 * 72 + seg * 16);
        uint4 d1 = *(const uint4*)(Cw + row16 * 72 + seg * 16 + 8);
        unsigned short* p = o + (size_t)(m0 + 16 * mt + row16) * A_ + seg * 16;
        *(uint4*)(p) = d0;
        *(uint4*)(p + 8) = d1;
    }
    __syncthreads();
    // v: combined store from both w=2 waves -> 64B contiguous per a-row
    if (t < 256) {
        const int a = t >> 2, quarter = t & 3;
        const int o = quarter * 8, mtv = o >> 4, idx = o & 15;
        uint4 d = *(const uint4*)(Cst + (4 + mtv) * 1536 + a * 24 + idx);
        const int bb = m0 >> 12, l0 = m0 & (L_ - 1);
        *(uint4*)(vto + ((size_t)(bb * A_ + a)) * L_ + l0 + o) = d;
    }
}

// ---------------------------------------------------------------------------
// attn: split-K flash. grid (256, B): bx -> (qt = 127-(bx>>1), h = bx&1).
// Each block: 32 queries, key-tile range [t0,t1) = half of T(qt) tiles.
// 4 waves = 2 qsub x 2 phase; K/V LDS-staged (V plain rows, no reorder).
// S^T form: QK^T A=K,B=Q -> S^T[key][q=c]; softmax per-lane q row (exp2);
// PV: A=V^T 8B LDS frags, B=P^T in registers (K=16 chain).
// Emits UNNORMALIZED partial (O,m,l): h=0 -> out, h=1 -> po1/ml1.
// ---------------------------------------------------------------------------
__global__ __launch_bounds__(256) void attn_kernel(
    const unsigned short* __restrict__ qb,  // [B][L][64] fp16 (x 1/ln2)
    const unsigned short* __restrict__ kb,  // [B][L][64] fp16
    const unsigned short* __restrict__ vt,  // [B][64][L] fp16
    float* __restrict__ out,                // partial O for h=0
    float* __restrict__ po1,                // partial O for h=1
    float2* __restrict__ ml0,               // (m,l) h=0  [B*L]
    float2* __restrict__ ml1)               // (m,l) h=1  [B*L]
{
    __shared__ __align__(16) unsigned short smem[4 * 4608];  // 36 KB
    unsigned short* Ks = smem;
    unsigned short* Vs = smem + 2 * 4608;

    const int t    = threadIdx.x;
    const int lane = t & 63;
    const int wid  = t >> 6;
    const int qsub = wid >> 1;
    const int ph   = wid & 1;
    const int c    = lane & 15;
    const int g    = lane >> 4;
    const int b    = blockIdx.y;
    const int bx   = blockIdx.x;
    const int qt   = 127 - (bx >> 1);     // heavy q-tiles first
    const int h    = bx & 1;
    const int q0   = qt * 32;
    const int qrow0 = q0 + 16 * qsub;
    const int qme  = qrow0 + c;

    const size_t base  = (size_t)b * L_ * A_;
    const size_t vbase = (size_t)b * A_ * L_;

    half8 qf[2];
    {
        const unsigned short* qp = qb + base + (size_t)(qrow0 + c) * A_ + g * 8;
        qf[0] = *(const half8*)(qp);
        qf[1] = *(const half8*)(qp + 32);
    }

    floatx4 O4[4];          // O^T[a=16at+4g+r][q=c], unnormalized
    #pragma unroll
    for (int at = 0; at < 4; ++at) O4[at] = (floatx4){0.f, 0.f, 0.f, 0.f};
    float m_ = -INFINITY, l_ = 0.f;

    const int T   = (q0 >> 6) + 1;
    const int Th  = (T + 1) >> 1;
    const int t0  = h ? Th : 0;
    const int t1  = h ? T : Th;
    const int nIt = (t1 - t0 + 1) >> 1;
    const int Tm1 = T - 1;

    for (int it = 0; it < nIt; ++it) {
        __syncthreads();
        #pragma unroll
        for (int tile = 0; tile < 2; ++tile) {
            const int kts = t0 + 2 * it + tile;
            if (kts < t1) {
                const int k0s = kts << 6;
                #pragma unroll
                for (int i = 0; i < 2; ++i) {
                    const int cid = t + (i << 8);
                    const int row = cid >> 3, c8 = cid & 7;
                    uint4 dK = *(const uint4*)(kb + base + (size_t)k0s * 64 + cid * 8);
                    *(uint4*)(Ks + tile * 4608 + row * 72 + c8 * 8) = dK;
                    uint4 dV = *(const uint4*)(vt + vbase + (size_t)row * L_ + k0s + c8 * 8);
                    *(uint4*)(Vs + tile * 4608 + row * 72 + c8 * 8) = dV;
                }
            }
        }
        __syncthreads();

        const int kt = t0 + 2 * it + ph;
        if (kt >= t1) continue;          // loop-top barriers stay convergent
        const int k0 = kt << 6;
        const unsigned short* Kw = Ks + ph * 4608;
        const unsigned short* Vw = Vs + ph * 4608;

        // ---- S^T = K . Q^T ----
        floatx4 S4[4];
        #pragma unroll
        for (int nt = 0; nt < 4; ++nt) S4[nt] = (floatx4){0.f, 0.f, 0.f, 0.f};
        #pragma unroll
        for (int s = 0; s < 2; ++s)
            #pragma unroll
            for (int nt = 0; nt < 4; ++nt) {
                half8 kf = *(const half8*)(Kw + (16 * nt + c) * 72 + 32 * s + 8 * g);
                S4[nt] = __builtin_amdgcn_mfma_f32_16x16x32_f16(kf, qf[s], S4[nt], 0, 0, 0);
            }

        // ---- causal mask: only global tile T-1 straddles the diagonal ----
        if (kt == Tm1) {
            #pragma unroll
            for (int nt = 0; nt < 4; ++nt)
                #pragma unroll
                for (int r = 0; r < 4; ++r)
                    if (k0 + 16 * nt + 4 * g + r > qme) S4[nt][r] = -INFINITY;
        }

        // ---- online softmax (exp2 domain; per-lane q row) ----
        float tm = fmaxf(fmaxf(fmaxf(S4[0][0], S4[0][1]), fmaxf(S4[0][2], S4[0][3])),
                         fmaxf(fmaxf(S4[1][0], S4[1][1]), fmaxf(S4[1][2], S4[1][3])));
        tm = fmaxf(tm, fmaxf(fmaxf(fmaxf(S4[2][0], S4[2][1]), fmaxf(S4[2][2], S4[2][3])),
                             fmaxf(fmaxf(S4[3][0], S4[3][1]), fmaxf(S4[3][2], S4[3][3]))));
        tm = fmaxf(tm, __shfl_xor(tm, 16));
        tm = fmaxf(tm, __shfl_xor(tm, 32));
        const float mn  = fmaxf(m_, tm);
        const float mnc = fmaxf(mn, -3.0e38f);         // guard -inf - -inf
        const float al  = exp2f(fminf(m_ - mnc, 0.f)); // m_=-inf -> 0
        float rs = 0.f;
        half4 pf[4];
        #pragma unroll
        for (int nt = 0; nt < 4; ++nt) {
            #pragma unroll
            for (int r = 0; r < 4; ++r) {
                float p = exp2f(S4[nt][r] - mnc);      // masked: exp2(-inf)=0
                S4[nt][r] = p;
                rs += p;
            }
            pf[nt][0] = (_Float16)S4[nt][0];
            pf[nt][1] = (_Float16)S4[nt][1];
            pf[nt][2] = (_Float16)S4[nt][2];
            pf[nt][3] = (_Float16)S4[nt][3];
        }
        rs += __shfl_xor(rs, 16);
        rs += __shfl_xor(rs, 32);
        l_ = l_ * al + rs;
        m_ = mn;

        // ---- O^T = O^T*al + V^T . P^T  (V A-frags: 8B LDS reads) ----
        #pragma unroll
        for (int at = 0; at < 4; ++at) {
            O4[at] *= al;
            #pragma unroll
            for (int nt = 0; nt < 4; ++nt) {
                half4 va = *(const half4*)(Vw + (16 * at + c) * 72 + 16 * nt + 4 * g);
                O4[at] = __builtin_amdgcn_mfma_f32_16x16x16f16(va, pf[nt], O4[at], 0, 0, 0);
            }
        }
    }

    // ---- combine 2 phases per qsub; write unnormalized partial ----
    __syncthreads();
    float*  Of  = (float*)smem;                 // [wid][at][lane][r]  16 KB
    float2* mlb = (float2*)(smem + 8192);       // [wid][c]  (byte off 16384)
    #pragma unroll
    for (int at = 0; at < 4; ++at) {
        float4 v; v.x = O4[at][0]; v.y = O4[at][1]; v.z = O4[at][2]; v.w = O4[at][3];
        ((float4*)Of)[wid * 256 + at * 64 + lane] = v;
    }
    if (g == 0) { float2 ml; ml.x = m_; ml.y = l_; mlb[wid * 16 + c] = ml; }
    __syncthreads();

    {
        const int q32 = t >> 3, seg = t & 7;
        const int qs = q32 >> 4, cc = q32 & 15;
        const float2 A0 = mlb[(2 * qs) * 16 + cc];
        const float2 A1 = mlb[(2 * qs + 1) * 16 + cc];
        const float mf = fmaxf(A0.x, A1.x);
        const float mc = fmaxf(mf, -3.0e38f);
        const float w0 = exp2f(A0.x - mc);      // -inf -> 0
        const float w1 = exp2f(A1.x - mc);
        const float ls = w0 * A0.y + w1 * A1.y;
        float res[8];
        #pragma unroll
        for (int u = 0; u < 8; ++u) {
            const int a = seg * 8 + u;
            const int at = a >> 4, gg = (a >> 2) & 3, r = a & 3;
            const int i0 = ((2 * qs) * 256 + at * 64 + gg * 16 + cc) * 4 + r;
            const int i1 = ((2 * qs + 1) * 256 + at * 64 + gg * 16 + cc) * 4 + r;
            res[u] = w0 * Of[i0] + w1 * Of[i1];
        }
        float* PO = h ? po1 : out;
        float* p = PO + (base + (size_t)(q0 + q32) * A_) + seg * 8;
        *(float4*)(p)     = make_float4(res[0], res[1], res[2], res[3]);
        *(float4*)(p + 4) = make_float4(res[4], res[5], res[6], res[7]);
        if (seg == 0) {
            float2 ml; ml.x = mf; ml.y = ls;
            (h ? ml1 : ml0)[b * L_ + q0 + q32] = ml;
        }
    }
}

// ---------------------------------------------------------------------------
// merge: final = (O0*w0 + O1*w1) / (l0*w0 + l1*w1). grid (1024), block 256.
// ---------------------------------------------------------------------------
__global__ __launch_bounds__(256) void merge_kernel(
    float* __restrict__ out, const float* __restrict__ po1,
    const float2* __restrict__ ml0, const float2* __restrict__ ml1)
{
    const int tg = blockIdx.x * 256 + threadIdx.x;   // 262144 float4s
    const int q = tg >> 4;
    const float2 a0 = ml0[q], a1 = ml1[q];
    const float mf = fmaxf(a0.x, a1.x);
    const float mc = fmaxf(mf, -3.0e38f);
    const float w0 = exp2f(a0.x - mc);
    const float w1 = exp2f(a1.x - mc);
    const float inv = 1.f / (w0 * a0.y + w1 * a1.y);
    float4 o0 = ((const float4*)out)[tg];
    float4 o1 = ((const float4*)po1)[tg];
    float4 r;
    r.x = (o0.x * w0 + o1.x * w1) * inv;
    r.y = (o0.y * w0 + o1.y * w1) * inv;
    r.z = (o0.z * w0 + o1.z * w1) * inv;
    r.w = (o0.w * w0 + o1.w * w1) * inv;
    ((float4*)out)[tg] = r;
}

// ---------------------------------------------------------------------------
extern "C" void kernel_launch(void* const* d_in, const int* in_sizes, int n_in,
                              void* d_out, int out_size, void* d_ws, size_t ws_size,
                              hipStream_t stream) {
    const float* x  = (const float*)d_in[0];
    const float* Wq = (const float*)d_in[1];
    const float* Wk = (const float*)d_in[2];
    const float* Wv = (const float*)d_in[3];

    char* ws = (char*)d_ws;
    unsigned short* qb = (unsigned short*)(ws);                    // 2 MB
    unsigned short* kb = (unsigned short*)(ws + (2u << 20));       // 2 MB
    unsigned short* vt = (unsigned short*)(ws + (4u << 20));       // 2 MB
    unsigned short* wt = (unsigned short*)(ws + (6u << 20));       // 96 KB
    float*  po1 = (float*) (ws + (6u << 20) + 98304);              // 4 MB
    float2* ml0 = (float2*)(ws + (6u << 20) + 98304 + (4u << 20));           // 128 KB
    float2* ml1 = (float2*)(ws + (6u << 20) + 98304 + (4u << 20) + 131072);  // 128 KB
    float* out = (float*)d_out;

    hipLaunchKernelGGL(wconv_kernel, dim3(3), dim3(256), 0, stream, Wq, Wk, Wv, wt);
    hipLaunchKernelGGL(proj_kernel, dim3(M_ / 32), dim3(384), 0, stream, x, wt, qb, kb, vt);
    hipLaunchKernelGGL(attn_kernel, dim3(256, B_), dim3(256), 0, stream,
                       qb, kb, vt, out, po1, ml0, ml1);
    hipLaunchKernelGGL(merge_kernel, dim3(1024), dim3(256), 0, stream, out, po1, ml0, ml1);
}